// Round 1
// baseline (91.727 us; speedup 1.0000x reference)
//
#include <hip/hip_runtime.h>

#define L_DIM 2048
#define H_DIM 8
#define E_DIM 64

typedef __attribute__((ext_vector_type(4))) short short4v;
typedef __attribute__((ext_vector_type(8))) short short8;
typedef __attribute__((ext_vector_type(4))) float f32x4;

__device__ __forceinline__ unsigned short f2bf(float f) {
  union { float f; unsigned u; } c; c.f = f;
  unsigned u = c.u;
  return (unsigned short)((u + 0x7fffu + ((u >> 16) & 1u)) >> 16);
}

// Read an 8-bf16 MFMA operand fragment from a swizzled 64x64-bf16 LDS tile.
// Logical layout: [row][64 e], row stride 128 B, 16 units of 8 B per row.
// Physical unit = logical unit ^ ((row&7)<<1).
// Fragment slots: j<4 -> elem 32*ec + 4*g + j ; j>=4 -> 32*ec + 16 + 4*g + (j-4).
__device__ __forceinline__ short8 read_frag(const unsigned char* base, int row, int ec, int g) {
  int p = (row & 7) << 1;
  short4v lo = *(const short4v*)(base + row * 128 + (((8 * ec + g) ^ p) << 3));
  short4v hi = *(const short4v*)(base + row * 128 + (((8 * ec + 4 + g) ^ p) << 3));
  return __builtin_shufflevector(lo, hi, 0, 1, 2, 3, 4, 5, 6, 7);
}

// Pre-pass: z=0: q -> qbf (bf16, [bh][l][e]) + qn2 ; z=1: k -> kbf + kn2 ;
// z=2: v -> vt (bf16, transposed [bh][e][s]).
__global__ __launch_bounds__(256) void prep_kernel(
    const float* __restrict__ qin, const float* __restrict__ kin, const float* __restrict__ vin,
    unsigned short* __restrict__ qbf, unsigned short* __restrict__ kbf,
    unsigned short* __restrict__ vtb, float* __restrict__ qn2, float* __restrict__ kn2) {
  __shared__ unsigned short vlds[64][68];
  int bh = blockIdx.y, z = blockIdx.z;
  int b = bh >> 3, h = bh & 7;
  int r0 = blockIdx.x * 64;
  int t = threadIdx.x;
  int row = t >> 2, quad = t & 3;

  const float* src = (z == 0) ? qin : (z == 1) ? kin : vin;
  const float* rp = src + (((size_t)(b * L_DIM + r0 + row) * H_DIM + h) * E_DIM + quad * 16);
  f32x4 fv[4];
#pragma unroll
  for (int i = 0; i < 4; ++i) fv[i] = ((const f32x4*)rp)[i];
  float vals[16];
#pragma unroll
  for (int i = 0; i < 16; ++i) vals[i] = fv[i / 4][i % 4];

  if (z < 2) {
    unsigned short* dst = (z == 0) ? qbf : kbf;
    float* n2 = (z == 0) ? qn2 : kn2;
    float ss = 0.f;
#pragma unroll
    for (int i = 0; i < 16; ++i) ss = fmaf(vals[i], vals[i], ss);
    ss += __shfl_xor(ss, 1);
    ss += __shfl_xor(ss, 2);
    unsigned pk[8];
#pragma unroll
    for (int i = 0; i < 8; ++i)
      pk[i] = (unsigned)f2bf(vals[2 * i]) | ((unsigned)f2bf(vals[2 * i + 1]) << 16);
    unsigned short* drow = dst + ((size_t)bh * L_DIM + r0 + row) * E_DIM + quad * 16;
    ((uint4*)drow)[0] = make_uint4(pk[0], pk[1], pk[2], pk[3]);
    ((uint4*)drow)[1] = make_uint4(pk[4], pk[5], pk[6], pk[7]);
    if (quad == 0) n2[(size_t)bh * L_DIM + r0 + row] = ss;
  } else {
#pragma unroll
    for (int i = 0; i < 16; ++i) vlds[row][quad * 16 + i] = f2bf(vals[i]);
    __syncthreads();
    int e = t >> 2, sq = t & 3;
    unsigned pk[8];
#pragma unroll
    for (int i = 0; i < 8; ++i)
      pk[i] = (unsigned)vlds[sq * 16 + 2 * i][e] | ((unsigned)vlds[sq * 16 + 2 * i + 1][e] << 16);
    unsigned short* drow = vtb + ((size_t)bh * E_DIM + e) * L_DIM + r0 + sq * 16;
    ((uint4*)drow)[0] = make_uint4(pk[0], pk[1], pk[2], pk[3]);
    ((uint4*)drow)[1] = make_uint4(pk[4], pk[5], pk[6], pk[7]);
  }
}

// Main: one block = 64 q rows of one (b,h); 4 waves x 16 q rows.
// QK^T: mfma(A=K, B=Q) -> scores col q = lane&15, row s = 4g+r (lane-local q!).
// PV:   mfma(A=Vt, B=P) -> O col q = lane&15, row e = 4g+r.
__global__ __launch_bounds__(256, 2) void attn_kernel(
    const unsigned short* __restrict__ qbf, const unsigned short* __restrict__ kbf,
    const unsigned short* __restrict__ vtb, const float* __restrict__ qn2g,
    const float* __restrict__ kn2g, float* __restrict__ outp) {
  __shared__ __align__(16) unsigned char Qs[8192];
  __shared__ __align__(16) unsigned char Ks[2][8192];
  __shared__ __align__(16) unsigned char Vs[2][8192];
  __shared__ float kn2s[2][64];

  // XCD-aware swizzle: 512 blocks, 64 consecutive work-units per XCD.
  int flat = blockIdx.y * 32 + blockIdx.x;
  int sw = (flat & 7) * 64 + (flat >> 3);
  int bh = sw >> 5;
  int q0 = (sw & 31) * 64;
  int b = bh >> 3, h = bh & 7;

  int t = threadIdx.x;
  int lane = t & 63, w = t >> 6;
  int l15 = lane & 15, g = lane >> 4;
  int m8 = t & 7, r32 = t >> 3;

  const unsigned short* kg = kbf + (size_t)bh * L_DIM * E_DIM;
  const unsigned short* vg = vtb + (size_t)bh * E_DIM * L_DIM;

  uint4 pk0, pk1, pv0, pv1;
  float pkn = 0.f;

  auto load_regs = [&](int s0) {
    const unsigned short* kq = kg + (size_t)s0 * E_DIM;
    pk0 = *(const uint4*)(kq + (size_t)r32 * 64 + 8 * m8);
    pk1 = *(const uint4*)(kq + (size_t)(r32 + 32) * 64 + 8 * m8);
    const unsigned short* vq = vg + s0;
    pv0 = *(const uint4*)(vq + (size_t)r32 * L_DIM + 8 * m8);
    pv1 = *(const uint4*)(vq + (size_t)(r32 + 32) * L_DIM + 8 * m8);
    if (t < 64) pkn = kn2g[(size_t)bh * L_DIM + s0 + t];
  };
  auto write_lds = [&](int buf) {
    int r2 = r32 + 32;
    int p0 = ((2 * m8) ^ ((r32 & 7) << 1)) << 3;
    int p1 = ((2 * m8) ^ ((r2 & 7) << 1)) << 3;
    *(uint4*)&Ks[buf][r32 * 128 + p0] = pk0;
    *(uint4*)&Ks[buf][r2 * 128 + p1] = pk1;
    *(uint4*)&Vs[buf][r32 * 128 + p0] = pv0;
    *(uint4*)&Vs[buf][r2 * 128 + p1] = pv1;
    if (t < 64) kn2s[buf][t] = pkn;
  };

  {  // stage Q tile (once)
    const unsigned short* qg = qbf + ((size_t)bh * L_DIM + q0) * E_DIM;
#pragma unroll
    for (int hh = 0; hh < 2; ++hh) {
      int row = r32 + 32 * hh;
      uint4 d = *(const uint4*)(qg + (size_t)row * 64 + 8 * m8);
      *(uint4*)&Qs[row * 128 + (((2 * m8) ^ ((row & 7) << 1)) << 3)] = d;
    }
  }
  load_regs(0);
  write_lds(0);
  __syncthreads();

  short8 qf0 = read_frag(Qs, w * 16 + l15, 0, g);
  short8 qf1 = read_frag(Qs, w * 16 + l15, 1, g);
  float qn2v = qn2g[(size_t)bh * L_DIM + q0 + w * 16 + l15];

  f32x4 o[4];
#pragma unroll
  for (int i = 0; i < 4; ++i) o[i] = (f32x4){0.f, 0.f, 0.f, 0.f};
  float mrun = -1e30f, lrun = 0.f;

  for (int it = 0; it < 32; ++it) {
    int cur = it & 1;
    if (it < 31) load_regs((it + 1) * 64);

    float p_[4][4];
#pragma unroll
    for (int st = 0; st < 4; ++st) {
      short8 kf0 = read_frag(Ks[cur], st * 16 + l15, 0, g);
      short8 kf1 = read_frag(Ks[cur], st * 16 + l15, 1, g);
      f32x4 c = (f32x4){0.f, 0.f, 0.f, 0.f};
      c = __builtin_amdgcn_mfma_f32_16x16x32_bf16(kf0, qf0, c, 0, 0, 0);
      c = __builtin_amdgcn_mfma_f32_16x16x32_bf16(kf1, qf1, c, 0, 0, 0);
#pragma unroll
      for (int r = 0; r < 4; ++r) {
        float dot = c[r];
        float k2 = kn2s[cur][st * 16 + 4 * g + r];
        float w2 = fmaf(qn2v, k2, -(dot * dot));
        p_[st][r] = 0.125f * sqrtf(fmaxf(w2, 0.f) + 1e-8f);
      }
    }

    // online softmax over this 64-s tile; state is lane-local (q = lane&15)
    float tmax = p_[0][0];
#pragma unroll
    for (int st = 0; st < 4; ++st)
#pragma unroll
      for (int r = 0; r < 4; ++r) tmax = fmaxf(tmax, p_[st][r]);
    tmax = fmaxf(tmax, __shfl_xor(tmax, 16));
    tmax = fmaxf(tmax, __shfl_xor(tmax, 32));
    float mnew = fmaxf(mrun, tmax);
    float fsc = __expf(mrun - mnew);
    float tsum = 0.f;
#pragma unroll
    for (int st = 0; st < 4; ++st)
#pragma unroll
      for (int r = 0; r < 4; ++r) {
        float e = __expf(p_[st][r] - mnew);
        p_[st][r] = e;
        tsum += e;
      }
    tsum += __shfl_xor(tsum, 16);
    tsum += __shfl_xor(tsum, 32);
    lrun = fmaf(lrun, fsc, tsum);
    mrun = mnew;

    short8 pf0, pf1;
#pragma unroll
    for (int j = 0; j < 4; ++j) {
      pf0[j] = (short)f2bf(p_[0][j]);
      pf0[j + 4] = (short)f2bf(p_[1][j]);
      pf1[j] = (short)f2bf(p_[2][j]);
      pf1[j + 4] = (short)f2bf(p_[3][j]);
    }
#pragma unroll
    for (int et = 0; et < 4; ++et) o[et] *= fsc;

#pragma unroll
    for (int et = 0; et < 4; ++et) {
      short8 vf0 = read_frag(Vs[cur], et * 16 + l15, 0, g);
      short8 vf1 = read_frag(Vs[cur], et * 16 + l15, 1, g);
      o[et] = __builtin_amdgcn_mfma_f32_16x16x32_bf16(vf0, pf0, o[et], 0, 0, 0);
      o[et] = __builtin_amdgcn_mfma_f32_16x16x32_bf16(vf1, pf1, o[et], 0, 0, 0);
    }

    if (it < 31) write_lds(cur ^ 1);
    __syncthreads();
  }

  float inv = 1.f / lrun;
  size_t ob = (((size_t)(b * L_DIM + q0 + w * 16 + l15)) * H_DIM + h) * E_DIM;
#pragma unroll
  for (int et = 0; et < 4; ++et) {
    o[et] *= inv;
    *(f32x4*)(outp + ob + 16 * et + 4 * g) = o[et];
  }
}

extern "C" void kernel_launch(void* const* d_in, const int* in_sizes, int n_in,
                              void* d_out, int out_size, void* d_ws, size_t ws_size,
                              hipStream_t stream) {
  const float* q = (const float*)d_in[0];
  const float* k = (const float*)d_in[1];
  const float* v = (const float*)d_in[2];
  float* out = (float*)d_out;
  unsigned char* ws = (unsigned char*)d_ws;
  unsigned short* qbf = (unsigned short*)(ws);
  unsigned short* kbf = (unsigned short*)(ws + ((size_t)4 << 20));
  unsigned short* vtb = (unsigned short*)(ws + ((size_t)8 << 20));
  float* qn2 = (float*)(ws + ((size_t)12 << 20));
  float* kn2 = (float*)(ws + ((size_t)12 << 20) + ((size_t)256 << 10));

  dim3 pg(32, 16, 3);
  prep_kernel<<<pg, 256, 0, stream>>>(q, k, v, qbf, kbf, vtb, qn2, kn2);
  dim3 mg(32, 16);
  attn_kernel<<<mg, 256, 0, stream>>>(qbf, kbf, vtb, qn2, kn2, out);
}

// Round 2
// 60.678 us; speedup vs baseline: 1.5117x; 1.5117x over previous
//
#include <hip/hip_runtime.h>

#define L_DIM 2048
#define H_DIM 8
#define E_DIM 64
#define C2 0.18033688f  // 0.125 * log2(e)

typedef __attribute__((ext_vector_type(4))) short short4v;
typedef __attribute__((ext_vector_type(8))) short short8;
typedef __attribute__((ext_vector_type(4))) float f32x4;

typedef const void __attribute__((address_space(1)))* gp1;
typedef void __attribute__((address_space(3)))* lp3;
__device__ __forceinline__ void gl_lds16(const void* g, void* l) {
  __builtin_amdgcn_global_load_lds((gp1)g, (lp3)l, 16, 0, 0);
}
__device__ __forceinline__ void gl_lds4(const void* g, void* l) {
  __builtin_amdgcn_global_load_lds((gp1)g, (lp3)l, 4, 0, 0);
}

__device__ __forceinline__ unsigned short f2bf(float f) {
  union { float f; unsigned u; } c; c.f = f;
  unsigned u = c.u;
  return (unsigned short)((u + 0x7fffu + ((u >> 16) & 1u)) >> 16);
}

__device__ __forceinline__ unsigned cvtpk(float lo, float hi) {
  unsigned r;
  asm("v_cvt_pk_bf16_f32 %0, %1, %2" : "=v"(r) : "v"(lo), "v"(hi));
  return r;
}

// Swizzled 64x64-bf16 LDS tile: row stride 128B, 16B chunk c at phys c^(row&7).
// Fragment slots: j<4 -> elem 32*ec + 4*g + j ; j>=4 -> 32*ec + 16 + 4*g + (j-4).
__device__ __forceinline__ short8 read_frag(const unsigned char* base, int row, int ec, int g) {
  int p = (row & 7) << 1;
  short4v lo = *(const short4v*)(base + row * 128 + (((8 * ec + g) ^ p) << 3));
  short4v hi = *(const short4v*)(base + row * 128 + (((8 * ec + 4 + g) ^ p) << 3));
  return __builtin_shufflevector(lo, hi, 0, 1, 2, 3, 4, 5, 6, 7);
}

// Pre-pass. Staged layouts (per bh, 32 tiles of 64 rows x 128B; 16B chunk c of a
// row stored at chunk c^(row&7)) so attn can global_load_lds linearly.
// z=0: q -> qstg + qn2 ; z=1: k -> kstg + kn2 ; z=2: v -> vstg ([e][s] tiles).
__global__ __launch_bounds__(256) void prep_kernel(
    const float* __restrict__ qin, const float* __restrict__ kin, const float* __restrict__ vin,
    unsigned short* __restrict__ qstg, unsigned short* __restrict__ kstg,
    unsigned short* __restrict__ vstg, float* __restrict__ qn2, float* __restrict__ kn2) {
  __shared__ unsigned short vlds[64][68];
  int bh = blockIdx.y, z = blockIdx.z;
  int b = bh >> 3, h = bh & 7;
  int r0 = blockIdx.x * 64;
  int t = threadIdx.x;
  int row = t >> 2, quad = t & 3;

  const float* src = (z == 0) ? qin : (z == 1) ? kin : vin;
  const float* rp = src + (((size_t)(b * L_DIM + r0 + row) * H_DIM + h) * E_DIM + quad * 16);
  f32x4 fv[4];
#pragma unroll
  for (int i = 0; i < 4; ++i) fv[i] = ((const f32x4*)rp)[i];
  float vals[16];
#pragma unroll
  for (int i = 0; i < 16; ++i) vals[i] = fv[i / 4][i % 4];

  if (z < 2) {
    unsigned short* dst = (z == 0) ? qstg : kstg;
    float* n2 = (z == 0) ? qn2 : kn2;
    float ss = 0.f;
#pragma unroll
    for (int i = 0; i < 16; ++i) ss = fmaf(vals[i], vals[i], ss);
    ss += __shfl_xor(ss, 1);
    ss += __shfl_xor(ss, 2);
    unsigned pk[8];
#pragma unroll
    for (int i = 0; i < 8; ++i)
      pk[i] = (unsigned)f2bf(vals[2 * i]) | ((unsigned)f2bf(vals[2 * i + 1]) << 16);
    size_t base_el = (size_t)bh * L_DIM * E_DIM + (size_t)blockIdx.x * 4096 + row * 64;
    int s7 = row & 7;
    int d0 = (2 * quad) ^ s7, d1 = (2 * quad + 1) ^ s7;
    *(uint4*)(dst + base_el + d0 * 8) = make_uint4(pk[0], pk[1], pk[2], pk[3]);
    *(uint4*)(dst + base_el + d1 * 8) = make_uint4(pk[4], pk[5], pk[6], pk[7]);
    if (quad == 0) n2[(size_t)bh * L_DIM + r0 + row] = ss;
  } else {
#pragma unroll
    for (int i = 0; i < 16; ++i) vlds[row][quad * 16 + i] = f2bf(vals[i]);
    __syncthreads();
    int e = t >> 2, sq = t & 3;
    unsigned pk[8];
#pragma unroll
    for (int i = 0; i < 8; ++i)
      pk[i] = (unsigned)vlds[sq * 16 + 2 * i][e] | ((unsigned)vlds[sq * 16 + 2 * i + 1][e] << 16);
    size_t base_el = (size_t)bh * E_DIM * L_DIM + (size_t)blockIdx.x * 4096 + e * 64;
    int s7 = e & 7;
    int d0 = (2 * sq) ^ s7, d1 = (2 * sq + 1) ^ s7;
    *(uint4*)(vstg + base_el + d0 * 8) = make_uint4(pk[0], pk[1], pk[2], pk[3]);
    *(uint4*)(vstg + base_el + d1 * 8) = make_uint4(pk[4], pk[5], pk[6], pk[7]);
  }
}

// Per-bh max of kn2 (for the fixed softmax bound).
__global__ __launch_bounds__(256) void kmax_kernel(const float* __restrict__ kn2,
                                                   float* __restrict__ kn2max) {
  int bh = blockIdx.x, t = threadIdx.x;
  float m = 0.f;
#pragma unroll
  for (int i = 0; i < 8; ++i) m = fmaxf(m, kn2[(size_t)bh * L_DIM + t + 256 * i]);
#pragma unroll
  for (int d = 1; d < 64; d <<= 1) m = fmaxf(m, __shfl_xor(m, d));
  __shared__ float red[4];
  if ((t & 63) == 0) red[t >> 6] = m;
  __syncthreads();
  if (t == 0) kn2max[bh] = fmaxf(fmaxf(red[0], red[1]), fmaxf(red[2], red[3]));
}

struct B0 { static constexpr int value = 0; };
struct B1 { static constexpr int value = 1; };

// One block = 64 q rows of one (b,h); 4 waves x 16 q rows; fixed per-row m.
__global__ __launch_bounds__(256, 2) void attn_kernel(
    const unsigned short* __restrict__ qst, const unsigned short* __restrict__ kst,
    const unsigned short* __restrict__ vst, const float* __restrict__ qn2g,
    const float* __restrict__ kn2g, const float* __restrict__ kn2maxg,
    float* __restrict__ outp) {
  __shared__ __align__(16) unsigned char Qs[8192];
  __shared__ __align__(16) unsigned char Ks[2][8192];
  __shared__ __align__(16) unsigned char Vs[2][8192];
  __shared__ __align__(16) float kn2s[2][64];

  int flat = blockIdx.y * 32 + blockIdx.x;
  int sw = (flat & 7) * 64 + (flat >> 3);
  int bh = sw >> 5;
  int q0 = (sw & 31) * 64;
  int b = bh >> 3, h = bh & 7;

  int t = threadIdx.x;
  int lane = t & 63, w = t >> 6;
  int l15 = lane & 15, g = lane >> 4;

  const char* kbase = (const char*)kst + (size_t)bh * (L_DIM * E_DIM * 2);
  const char* vbase = (const char*)vst + (size_t)bh * (L_DIM * E_DIM * 2);
  const float* kn2p = kn2g + (size_t)bh * L_DIM;

  {  // stage Q tile (once)
    const char* qb = (const char*)qst + (size_t)bh * (L_DIM * E_DIM * 2) +
                     (size_t)(q0 >> 6) * 8192 + w * 2048 + lane * 16;
    gl_lds16(qb, Qs + w * 2048);
    gl_lds16(qb + 1024, Qs + w * 2048 + 1024);
  }

  auto stage = [&](auto BC, int tile) {
    constexpr int B = decltype(BC)::value;
    const char* ksrc = kbase + (size_t)tile * 8192 + w * 2048 + lane * 16;
    const char* vsrc = vbase + (size_t)tile * 8192 + w * 2048 + lane * 16;
    gl_lds16(ksrc, (char*)Ks[B] + w * 2048);
    gl_lds16(ksrc + 1024, (char*)Ks[B] + w * 2048 + 1024);
    gl_lds16(vsrc, (char*)Vs[B] + w * 2048);
    gl_lds16(vsrc + 1024, (char*)Vs[B] + w * 2048 + 1024);
    if (w == 0) gl_lds4(kn2p + tile * 64 + lane, (void*)kn2s[B]);
  };

  stage(B0{}, 0);
  __syncthreads();

  short8 qf0 = read_frag(Qs, w * 16 + l15, 0, g);
  short8 qf1 = read_frag(Qs, w * 16 + l15, 1, g);
  float qn2v = qn2g[(size_t)bh * L_DIM + q0 + w * 16 + l15];
  float mneg = -(C2 * __builtin_amdgcn_sqrtf(qn2v * kn2maxg[bh]));

  f32x4 o[4];
#pragma unroll
  for (int i = 0; i < 4; ++i) o[i] = (f32x4){0.f, 0.f, 0.f, 0.f};
  float lrun = 0.f;

  auto compute = [&](auto BC) {
    constexpr int B = decltype(BC)::value;
    float p_[4][4];
#pragma unroll
    for (int st = 0; st < 4; ++st) {
      short8 kf0 = read_frag(Ks[B], st * 16 + l15, 0, g);
      short8 kf1 = read_frag(Ks[B], st * 16 + l15, 1, g);
      f32x4 c = (f32x4){0.f, 0.f, 0.f, 0.f};
      c = __builtin_amdgcn_mfma_f32_16x16x32_bf16(kf0, qf0, c, 0, 0, 0);
      c = __builtin_amdgcn_mfma_f32_16x16x32_bf16(kf1, qf1, c, 0, 0, 0);
      f32x4 k2 = *(const f32x4*)&kn2s[B][st * 16 + 4 * g];
#pragma unroll
      for (int r = 0; r < 4; ++r) {
        float w2 = fmaf(qn2v, k2[r], -(c[r] * c[r]));
        float s_ = __builtin_amdgcn_sqrtf(fmaxf(w2, 0.f));
        float p = __builtin_amdgcn_exp2f(fmaf(C2, s_, mneg));
        p_[st][r] = p;
        lrun += p;
      }
    }
    union U8 { unsigned u[4]; short8 s; } a_, b_;
    a_.u[0] = cvtpk(p_[0][0], p_[0][1]);
    a_.u[1] = cvtpk(p_[0][2], p_[0][3]);
    a_.u[2] = cvtpk(p_[1][0], p_[1][1]);
    a_.u[3] = cvtpk(p_[1][2], p_[1][3]);
    b_.u[0] = cvtpk(p_[2][0], p_[2][1]);
    b_.u[1] = cvtpk(p_[2][2], p_[2][3]);
    b_.u[2] = cvtpk(p_[3][0], p_[3][1]);
    b_.u[3] = cvtpk(p_[3][2], p_[3][3]);
#pragma unroll
    for (int et = 0; et < 4; ++et) {
      short8 vf0 = read_frag(Vs[B], et * 16 + l15, 0, g);
      short8 vf1 = read_frag(Vs[B], et * 16 + l15, 1, g);
      o[et] = __builtin_amdgcn_mfma_f32_16x16x32_bf16(vf0, a_.s, o[et], 0, 0, 0);
      o[et] = __builtin_amdgcn_mfma_f32_16x16x32_bf16(vf1, b_.s, o[et], 0, 0, 0);
    }
  };

  for (int it = 0; it < 32; it += 2) {
    stage(B1{}, it + 1);
    compute(B0{});
    __syncthreads();
    if (it + 2 < 32) stage(B0{}, it + 2);
    compute(B1{});
    __syncthreads();
  }

  lrun += __shfl_xor(lrun, 16);
  lrun += __shfl_xor(lrun, 32);
  float inv = 1.f / lrun;
  size_t ob = (((size_t)(b * L_DIM + q0 + w * 16 + l15)) * H_DIM + h) * E_DIM;
#pragma unroll
  for (int et = 0; et < 4; ++et) {
    f32x4 r = o[et] * inv;
    *(f32x4*)(outp + ob + 16 * et + 4 * g) = r;
  }
}

extern "C" void kernel_launch(void* const* d_in, const int* in_sizes, int n_in,
                              void* d_out, int out_size, void* d_ws, size_t ws_size,
                              hipStream_t stream) {
  const float* q = (const float*)d_in[0];
  const float* k = (const float*)d_in[1];
  const float* v = (const float*)d_in[2];
  float* out = (float*)d_out;
  unsigned char* ws = (unsigned char*)d_ws;
  unsigned short* qstg = (unsigned short*)(ws);
  unsigned short* kstg = (unsigned short*)(ws + ((size_t)4 << 20));
  unsigned short* vstg = (unsigned short*)(ws + ((size_t)8 << 20));
  float* qn2 = (float*)(ws + ((size_t)12 << 20));
  float* kn2 = (float*)(ws + ((size_t)12 << 20) + ((size_t)256 << 10));
  float* kn2max = (float*)(ws + ((size_t)12 << 20) + ((size_t)512 << 10));

  dim3 pg(32, 16, 3);
  prep_kernel<<<pg, 256, 0, stream>>>(q, k, v, qstg, kstg, vstg, qn2, kn2);
  kmax_kernel<<<16, 256, 0, stream>>>(kn2, kn2max);
  dim3 mg(32, 16);
  attn_kernel<<<mg, 256, 0, stream>>>(qstg, kstg, vstg, qn2, kn2, kn2max, out);
}